// Round 5
// baseline (6663.680 us; speedup 1.0000x reference)
//
#include <hip/hip_runtime.h>
#include <math.h>

#define BSZ 1024
#define SLEN 32
#define TLEN 32
#define EDIM 128
#define NBLK 256u

typedef unsigned short u16;
typedef __attribute__((ext_vector_type(8))) short bf16x8;
typedef __attribute__((ext_vector_type(4))) float f32x4;

__device__ __forceinline__ float sgm(float x) { return 1.0f / (1.0f + __expf(-x)); }
__device__ __forceinline__ float tanh_fast(float x) {
  float e = __expf(-2.0f * fabsf(x));
  float t = (1.0f - e) / (1.0f + e);
  return copysignf(t, x);
}

__device__ __forceinline__ u16 f2b(float f) {
  union { float f; unsigned u; } v; v.f = f;
  unsigned r = v.u + 0x7fffu + ((v.u >> 16) & 1u);
  return (u16)(r >> 16);
}
__device__ __forceinline__ float b2f(u16 h) {
  union { unsigned u; float f; } v; v.u = ((unsigned)h) << 16; return v.f;
}
__device__ __forceinline__ void unpk(unsigned p, float& x, float& y) {
  union { unsigned u; float f; } a, b;
  a.u = p << 16; b.u = p & 0xffff0000u;
  x = a.f; y = b.f;
}

typedef __attribute__((address_space(1))) const void gv_t;
typedef __attribute__((address_space(3))) void lv_t;
__device__ __forceinline__ void gload16(const void* g, void* l) {
  __builtin_amdgcn_global_load_lds((gv_t*)g, (lv_t*)l, 16, 0, 0);
}

// ---------------- device-scope generation grid barrier ---------------------------
__device__ __forceinline__ void gbar(unsigned* cnt, unsigned* gen) {
  __syncthreads();
  if (threadIdx.x == 0) {
    unsigned g = __hip_atomic_load(gen, __ATOMIC_RELAXED, __HIP_MEMORY_SCOPE_AGENT);
    unsigned a = __hip_atomic_fetch_add(cnt, 1u, __ATOMIC_ACQ_REL, __HIP_MEMORY_SCOPE_AGENT);
    if (a == NBLK - 1u) {
      __hip_atomic_store(cnt, 0u, __ATOMIC_RELAXED, __HIP_MEMORY_SCOPE_AGENT);
      __hip_atomic_store(gen, g + 1u, __ATOMIC_RELEASE, __HIP_MEMORY_SCOPE_AGENT);
    } else {
      while (__hip_atomic_load(gen, __ATOMIC_ACQUIRE, __HIP_MEMORY_SCOPE_AGENT) == g)
        __builtin_amdgcn_s_sleep(1);
    }
  }
  __syncthreads();
}

__global__ __launch_bounds__(64) void k_init_bar(unsigned* p) {
  if (threadIdx.x < 2) p[threadIdx.x] = 0u;
}

// ---------------- gi tables: tab[v][g] = bih[g] + emb[v]@Wih[g,:E] (fp32) ---------
__global__ __launch_bounds__(256) void k_gi_table(const float* __restrict__ emb,
                                                  const float* __restrict__ Wih, int ldw,
                                                  const float* __restrict__ bih,
                                                  float* __restrict__ tab) {
  int v = blockIdx.x;
  int g = blockIdx.y * 256 + threadIdx.x;
  __shared__ float e[EDIM];
  if (threadIdx.x < EDIM) e[threadIdx.x] = emb[v * EDIM + threadIdx.x];
  __syncthreads();
  const float4* w4 = (const float4*)(Wih + (size_t)g * ldw);
  float acc = 0.f;
#pragma unroll
  for (int j = 0; j < EDIM / 4; ++j) {
    float4 w = w4[j];
    acc += w.x * e[4 * j] + w.y * e[4 * j + 1] + w.z * e[4 * j + 2] + w.w * e[4 * j + 3];
  }
  tab[(size_t)v * 768 + g] = acc + bih[g];
}

// ---------------- fp32 -> bf16 weight pack ---------------------------------------
__global__ __launch_bounds__(256) void k_pack(u16* __restrict__ dst,
                                              const float* __restrict__ src, int ld,
                                              int off, int n) {
  int r = blockIdx.x;
  for (int c = threadIdx.x; c < n; c += 256)
    dst[(size_t)r * n + c] = f2b(src[(size_t)r * ld + off + c]);
}

// gates B matrix (1024 x 768)
__global__ __launch_bounds__(256) void k_pack_gates(u16* __restrict__ Wg,
                                                    const float* __restrict__ dWih,
                                                    const float* __restrict__ dWhh) {
  int r = blockIdx.x;
  for (int c = threadIdx.x; c < 768; c += 256) {
    float v;
    if (r < 512)      v = (c < 512) ? dWih[(size_t)r * 640 + 128 + c] : dWhh[(size_t)r * 256 + (c - 512)];
    else if (r < 768) v = (c < 512) ? dWih[(size_t)r * 640 + 128 + c] : 0.f;
    else              v = (c < 512) ? 0.f : dWhh[(size_t)(r - 256) * 256 + (c - 512)];
    Wg[(size_t)r * 768 + c] = f2b(v);
  }
}

// ---------------- bf16 MFMA GEMM 128x64 (enc_pre) --------------------------------
__global__ __launch_bounds__(256) void k_bgemm_b16(const u16* __restrict__ A, int lda,
                                                   const u16* __restrict__ B, int ldb,
                                                   const float* __restrict__ bias,
                                                   u16* __restrict__ out, int ldo, int K) {
  __shared__ u16 sA[128 * 64];
  __shared__ u16 sB[64 * 64];
  int m0 = blockIdx.x * 128, n0 = blockIdx.y * 64;
  int tid = threadIdx.x, w = tid >> 6, l = tid & 63;
  int wr = w >> 1, wc = w & 1;
  f32x4 acc[4][2] = {};
  for (int k0 = 0; k0 < K; k0 += 64) {
    __syncthreads();
#pragma unroll
    for (int i = 0; i < 4; ++i) {
      int chunk = i * 4 + w;
      int d = chunk * 1024 + l * 16;
      int lg = d ^ (((d >> 7) & 7) << 4);
      int row = lg >> 7, kb = lg & 127;
      gload16((const char*)(A + (size_t)(m0 + row) * lda + k0) + kb, (char*)sA + chunk * 1024);
    }
#pragma unroll
    for (int i = 0; i < 2; ++i) {
      int chunk = i * 4 + w;
      int d = chunk * 1024 + l * 16;
      int lg = d ^ (((d >> 7) & 7) << 4);
      int row = lg >> 7, kb = lg & 127;
      gload16((const char*)(B + (size_t)(n0 + row) * ldb + k0) + kb, (char*)sB + chunk * 1024);
    }
    __syncthreads();
#pragma unroll
    for (int kk = 0; kk < 2; ++kk) {
      bf16x8 av[4], bv[2];
#pragma unroll
      for (int fm = 0; fm < 4; ++fm) {
        int row = wr * 64 + fm * 16 + (l & 15);
        int addr = (row * 128 + kk * 64 + (l >> 4) * 16) ^ ((row & 7) << 4);
        av[fm] = *(const bf16x8*)((const char*)sA + addr);
      }
#pragma unroll
      for (int fn = 0; fn < 2; ++fn) {
        int row = wc * 32 + fn * 16 + (l & 15);
        int addr = (row * 128 + kk * 64 + (l >> 4) * 16) ^ ((row & 7) << 4);
        bv[fn] = *(const bf16x8*)((const char*)sB + addr);
      }
#pragma unroll
      for (int fm = 0; fm < 4; ++fm)
#pragma unroll
        for (int fn = 0; fn < 2; ++fn)
          acc[fm][fn] = __builtin_amdgcn_mfma_f32_16x16x32_bf16(av[fm], bv[fn], acc[fm][fn], 0, 0, 0);
    }
  }
#pragma unroll
  for (int fn = 0; fn < 2; ++fn) {
    int c = n0 + wc * 32 + fn * 16 + (l & 15);
    float bb = bias ? bias[c] : 0.f;
#pragma unroll
    for (int fm = 0; fm < 4; ++fm) {
      int r = m0 + wr * 64 + fm * 16 + (l >> 4) * 4;
#pragma unroll
      for (int j = 0; j < 4; ++j)
        out[(size_t)(r + j) * ldo + c] = f2b(acc[fm][fn][j] + bb);
    }
  }
}

// ---------------- shared 64x32 bf16 MFMA tile (4 waves x 16 rows, 32 cols) -------
__device__ __forceinline__ void tile_gemm64x32(const u16* Ab, int lda, const u16* Bb,
                                               int ldb, int K, u16* sA, u16* sB, int w,
                                               int l, f32x4* acc) {
  for (int k0 = 0; k0 < K; k0 += 64) {
    __syncthreads();
#pragma unroll
    for (int i = 0; i < 2; ++i) {
      int chunk = i * 4 + w;
      int d = chunk * 1024 + l * 16;
      int lg = d ^ (((d >> 7) & 7) << 4);
      int row = lg >> 7, kb = lg & 127;
      gload16((const char*)(Ab + (size_t)row * lda + k0) + kb, (char*)sA + chunk * 1024);
    }
    {
      int d = w * 1024 + l * 16;
      int lg = d ^ (((d >> 7) & 7) << 4);
      int row = lg >> 7, kb = lg & 127;
      gload16((const char*)(Bb + (size_t)row * ldb + k0) + kb, (char*)sB + w * 1024);
    }
    __syncthreads();
#pragma unroll
    for (int kk = 0; kk < 2; ++kk) {
      int arow = w * 16 + (l & 15);
      int aaddr = (arow * 128 + kk * 64 + (l >> 4) * 16) ^ ((arow & 7) << 4);
      bf16x8 av = *(const bf16x8*)((const char*)sA + aaddr);
#pragma unroll
      for (int fn = 0; fn < 2; ++fn) {
        int brow = fn * 16 + (l & 15);
        int baddr = (brow * 128 + kk * 64 + (l >> 4) * 16) ^ ((brow & 7) << 4);
        bf16x8 bv = *(const bf16x8*)((const char*)sB + baddr);
        acc[fn] = __builtin_amdgcn_mfma_f32_16x16x32_bf16(av, bv, acc[fn], 0, 0, 0);
      }
    }
  }
}

// ---------------- persistent encoder (spin-barrier) ------------------------------
struct EncArgs {
  float* enc_out; u16* enc_b; const int* src;
  const u16* Whhf; const u16* Whhb;
  const float* bhhf; const float* bhhb;
  const float* tabf; const float* tabb;
  unsigned* cnt; unsigned* gen;
};

__global__ __launch_bounds__(256) void k_enc(EncArgs E) {
  __shared__ __align__(16) char smem[20992];
  u16* sA = (u16*)smem;
  u16* sB = (u16*)(smem + 8192);
  int* tokL = (int*)(smem + 20480);
  int tile = blockIdx.x;
  int dir = tile >> 7, rem = tile & 127;
  int m0 = (rem >> 3) * 64, c0 = (rem & 7) * 32;
  int tid = threadIdx.x, w = tid >> 6, l = tid & 63;
  const u16* Whh = dir ? E.Whhb : E.Whhf;
  const float* bhh = dir ? E.bhhb : E.bhhf;
  const float* tab = dir ? E.tabb : E.tabf;
  for (int s = 0; s < SLEN; ++s) {
    int s_store = dir ? (SLEN - 1 - s) : s;
    int s_prev = dir ? (s_store + 1) : (s_store - 1);
    if (tid < 64) tokL[tid] = E.src[(size_t)(m0 + tid) * SLEN + s_store];
    __syncthreads();
    f32x4 acc[3][2] = {};
    if (s > 0) {
      const u16* hp = E.enc_b + (size_t)s_prev * 512 + dir * 256;
      for (int k0 = 0; k0 < 256; k0 += 64) {
        __syncthreads();
#pragma unroll
        for (int i = 0; i < 2; ++i) {
          int chunk = i * 4 + w;
          int d = chunk * 1024 + l * 16;
          int lg = d ^ (((d >> 7) & 7) << 4);
          int row = lg >> 7, kb = lg & 127;
          gload16((const char*)(hp + (size_t)(m0 + row) * 16384 + k0) + kb,
                  (char*)sA + chunk * 1024);
        }
#pragma unroll
        for (int i = 0; i < 3; ++i) {
          int chunk = i * 4 + w;
          int d = chunk * 1024 + l * 16;
          int lg = d ^ (((d >> 7) & 7) << 4);
          int tr = lg >> 7, kb = lg & 127;
          int g = tr >> 5, cc = tr & 31;
          gload16((const char*)(Whh + (size_t)(g * 256 + c0 + cc) * 256 + k0) + kb,
                  (char*)sB + chunk * 1024);
        }
        __syncthreads();
#pragma unroll
        for (int kk = 0; kk < 2; ++kk) {
          int arow = w * 16 + (l & 15);
          int aaddr = (arow * 128 + kk * 64 + (l >> 4) * 16) ^ ((arow & 7) << 4);
          bf16x8 av = *(const bf16x8*)((const char*)sA + aaddr);
#pragma unroll
          for (int g = 0; g < 3; ++g)
#pragma unroll
            for (int fn = 0; fn < 2; ++fn) {
              int br = g * 32 + fn * 16 + (l & 15);
              int baddr = (br * 128 + kk * 64 + (l >> 4) * 16) ^ ((br & 7) << 4);
              bf16x8 bv = *(const bf16x8*)((const char*)sB + baddr);
              acc[g][fn] = __builtin_amdgcn_mfma_f32_16x16x32_bf16(av, bv, acc[g][fn], 0, 0, 0);
            }
        }
      }
    }
#pragma unroll
    for (int fn = 0; fn < 2; ++fn) {
      int c = c0 + fn * 16 + (l & 15);
      float bR = bhh[c], bZ = bhh[256 + c], bN = bhh[512 + c];
#pragma unroll
      for (int j = 0; j < 4; ++j) {
        int rr = w * 16 + (l >> 4) * 4 + j;
        int row = m0 + rr;
        const float* tb = tab + (size_t)tokL[rr] * 768 + c;
        float hold = (s > 0) ? E.enc_out[((size_t)row * SLEN + s_prev) * 512 + dir * 256 + c] : 0.f;
        float rg = sgm(tb[0] + acc[0][fn][j] + bR);
        float zg = sgm(tb[256] + acc[1][fn][j] + bZ);
        float ng = tanh_fast(tb[512] + rg * (acc[2][fn][j] + bN));
        float hn = (1.f - zg) * ng + zg * hold;
        size_t oi = ((size_t)row * SLEN + s_store) * 512 + dir * 256 + c;
        E.enc_out[oi] = hn;
        E.enc_b[oi] = f2b(hn);
      }
    }
    if (s < SLEN - 1) gbar(E.cnt, E.gen);
  }
}

// ---------------- persistent decoder (spin-barrier) ------------------------------
struct DecArgs {
  const u16* enc_b; const u16* enc_pre_b; const float* v_attn;
  const u16* Wd_b; const u16* Wg; const u16* Wfc_b;
  const float* tabd; const float* dbhh; const float* bfc;
  const int* trg;
  u16* cat0; u16* cat1; float* h0f; float* h1f; float* dout;
  unsigned* cnt; unsigned* gen;
};

// fused attention for 8 rows (b0..b0+7): hWd (MFMA) + scores + softmax + ctx
__device__ void attn8(const DecArgs& A, u16* catn, int b0, char* smem, int tid, int w,
                      int l) {
  float* hwS = (float*)smem;           // 8 x 256
  float* vS = (float*)(smem + 8192);   // 256
  float* awS = (float*)(smem + 9216);  // 8 x 32
  vS[tid] = A.v_attn[tid];
  // hWd: wave w covers attn cols [64w, 64w+64)
  f32x4 acc[4] = {};
  for (int k0 = 0; k0 < 256; k0 += 32) {
    bf16x8 av = *(const bf16x8*)(catn + (size_t)(b0 + (l & 15)) * 768 + 512 + k0 + (l >> 4) * 8);
#pragma unroll
    for (int fn = 0; fn < 4; ++fn) {
      bf16x8 bv = *(const bf16x8*)(A.Wd_b + (size_t)(w * 64 + fn * 16 + (l & 15)) * 256 +
                                   k0 + (l >> 4) * 8);
      acc[fn] = __builtin_amdgcn_mfma_f32_16x16x32_bf16(av, bv, acc[fn], 0, 0, 0);
    }
  }
#pragma unroll
  for (int fn = 0; fn < 4; ++fn) {
    int c = w * 64 + fn * 16 + (l & 15);
#pragma unroll
    for (int j = 0; j < 4; ++j) {
      int r = (l >> 4) * 4 + j;
      if (r < 8) hwS[r * 256 + c] = acc[fn][j];
    }
  }
  __syncthreads();
  // scores: thread -> (r = tid>>5, s = tid&31)
  int r = tid >> 5, s = tid & 31;
  const u16* ep = A.enc_pre_b + ((size_t)(b0 + r) * SLEN + s) * 256;
  float sum = 0.f;
  for (int a0 = 0; a0 < 256; a0 += 8) {
    bf16x8 pk = *(const bf16x8*)(ep + a0);
    float4 h0 = *(const float4*)&hwS[r * 256 + a0];
    float4 h1 = *(const float4*)&hwS[r * 256 + a0 + 4];
    float4 v0 = *(const float4*)&vS[a0];
    float4 v1 = *(const float4*)&vS[a0 + 4];
    sum += v0.x * tanh_fast(b2f((u16)pk[0]) + h0.x) + v0.y * tanh_fast(b2f((u16)pk[1]) + h0.y) +
           v0.z * tanh_fast(b2f((u16)pk[2]) + h0.z) + v0.w * tanh_fast(b2f((u16)pk[3]) + h0.w) +
           v1.x * tanh_fast(b2f((u16)pk[4]) + h1.x) + v1.y * tanh_fast(b2f((u16)pk[5]) + h1.y) +
           v1.z * tanh_fast(b2f((u16)pk[6]) + h1.z) + v1.w * tanh_fast(b2f((u16)pk[7]) + h1.w);
  }
  float m = sum;
#pragma unroll
  for (int o = 16; o >= 1; o >>= 1) m = fmaxf(m, __shfl_xor(m, o));
  float e = __expf(sum - m), ss = e;
#pragma unroll
  for (int o = 16; o >= 1; o >>= 1) ss += __shfl_xor(ss, o);
  awS[r * 32 + s] = e / ss;
  __syncthreads();
  // ctx: thread -> cols [2*tid, 2*tid+2)
  int c = tid * 2;
#pragma unroll
  for (int rr = 0; rr < 8; ++rr) {
    float ax = 0.f, ay = 0.f;
    const u16* eb = A.enc_b + (size_t)(b0 + rr) * (SLEN * 512) + c;
#pragma unroll 8
    for (int si = 0; si < 32; ++si) {
      float a = awS[rr * 32 + si];
      unsigned pk = *(const unsigned*)(eb + si * 512);
      float x, y; unpk(pk, x, y);
      ax += a * x; ay += a * y;
    }
    *(unsigned*)(catn + (size_t)(b0 + rr) * 768 + c) =
        (unsigned)f2b(ax) | ((unsigned)f2b(ay) << 16);
  }
}

__global__ __launch_bounds__(256) void k_dec(DecArgs A) {
  __shared__ __align__(16) char smem[24832];
  int blk = blockIdx.x, tid = threadIdx.x, w = tid >> 6, l = tid & 63;
  // prologue: attn(0) on blocks >=128 (reads cat0[512:768]=h0, writes cat0[0:512])
  if (blk >= 128) attn8(A, A.cat0, (blk - 128) * 8, smem, tid, w, l);
  gbar(A.cnt, A.gen);
  for (int t = 0; t <= 30; ++t) {
    u16* catc = (t & 1) ? A.cat1 : A.cat0;
    u16* catn = (t & 1) ? A.cat0 : A.cat1;
    const float* hc = (t & 1) ? A.h1f : A.h0f;
    float* hn = (t & 1) ? A.h0f : A.h1f;
    float* doutT = A.dout + (size_t)(t + 1) * 256;
    // ---- Phase A: gates (blk<128) || logits-ctx (blk>=128) ----
    if (blk < 128) {
      u16* sA = (u16*)smem;
      u16* sB = (u16*)(smem + 8192);
      int* tokL = (int*)(smem + 24576);
      int m0 = (blk >> 3) * 64, c0 = (blk & 7) * 32;
      if (tid < 64) tokL[tid] = A.trg[(size_t)(m0 + tid) * TLEN + t];
      f32x4 acc[4][2] = {};
      for (int k0 = 0; k0 < 768; k0 += 64) {
        __syncthreads();
#pragma unroll
        for (int i = 0; i < 2; ++i) {
          int chunk = i * 4 + w;
          int d = chunk * 1024 + l * 16;
          int lg = d ^ (((d >> 7) & 7) << 4);
          int row = lg >> 7, kb = lg & 127;
          gload16((const char*)(catc + (size_t)(m0 + row) * 768 + k0) + kb,
                  (char*)sA + chunk * 1024);
        }
#pragma unroll
        for (int i = 0; i < 4; ++i) {
          int chunk = i * 4 + w;
          int d = chunk * 1024 + l * 16;
          int lg = d ^ (((d >> 7) & 7) << 4);
          int tr = lg >> 7, kb = lg & 127;
          int g = tr >> 5, cc = tr & 31;
          gload16((const char*)(A.Wg + (size_t)(g * 256 + c0 + cc) * 768 + k0) + kb,
                  (char*)sB + chunk * 1024);
        }
        __syncthreads();
#pragma unroll
        for (int kk = 0; kk < 2; ++kk) {
          int arow = w * 16 + (l & 15);
          int aaddr = (arow * 128 + kk * 64 + (l >> 4) * 16) ^ ((arow & 7) << 4);
          bf16x8 av = *(const bf16x8*)((const char*)sA + aaddr);
#pragma unroll
          for (int g = 0; g < 4; ++g)
#pragma unroll
            for (int fn = 0; fn < 2; ++fn) {
              int br = g * 32 + fn * 16 + (l & 15);
              int baddr = (br * 128 + kk * 64 + (l >> 4) * 16) ^ ((br & 7) << 4);
              bf16x8 bv = *(const bf16x8*)((const char*)sB + baddr);
              acc[g][fn] = __builtin_amdgcn_mfma_f32_16x16x32_bf16(av, bv, acc[g][fn], 0, 0, 0);
            }
        }
      }
#pragma unroll
      for (int fn = 0; fn < 2; ++fn) {
        int c = c0 + fn * 16 + (l & 15);
        float bR = A.dbhh[c], bZ = A.dbhh[256 + c], bN = A.dbhh[512 + c];
#pragma unroll
        for (int j = 0; j < 4; ++j) {
          int rr = w * 16 + (l >> 4) * 4 + j;
          int row = m0 + rr;
          const float* tb = A.tabd + (size_t)tokL[rr] * 768 + c;
          float rg = sgm(tb[0] + acc[0][fn][j] + bR);
          float zg = sgm(tb[256] + acc[1][fn][j] + bZ);
          float ng = tanh_fast(tb[512] + acc[2][fn][j] + rg * (acc[3][fn][j] + bN));
          float hold = hc[(size_t)row * 256 + c];
          float hv = (1.f - zg) * ng + zg * hold;
          hn[(size_t)row * 256 + c] = hv;
          catn[(size_t)row * 768 + 512 + c] = f2b(hv);
        }
      }
    } else {
      int idx = blk - 128;
      int m0 = (idx >> 3) * 64, n0 = (idx & 7) * 32;
      u16* sA = (u16*)smem;
      u16* sB = (u16*)(smem + 8192);
      f32x4 acc[2] = {};
      tile_gemm64x32(catc + (size_t)m0 * 768, 768, A.Wfc_b + (size_t)n0 * 768 + 256, 768,
                     512, sA, sB, w, l, acc);
#pragma unroll
      for (int fn = 0; fn < 2; ++fn) {
        int c = n0 + fn * 16 + (l & 15);
        float bb = A.bfc[c];
#pragma unroll
        for (int j = 0; j < 4; ++j) {
          int row = m0 + w * 16 + (l >> 4) * 4 + j;
          doutT[(size_t)row * (TLEN * 256) + c] = acc[fn][j] + bb;
        }
      }
    }
    gbar(A.cnt, A.gen);
    // ---- Phase B: logits-hn += (blk<128) || attn(t+1) (blk>=128) ----
    if (blk < 128) {
      int m0 = (blk >> 3) * 64, n0 = (blk & 7) * 32;
      u16* sA = (u16*)smem;
      u16* sB = (u16*)(smem + 8192);
      f32x4 acc[2] = {};
      tile_gemm64x32(catn + (size_t)m0 * 768 + 512, 768, A.Wfc_b + (size_t)n0 * 768, 768,
                     256, sA, sB, w, l, acc);
#pragma unroll
      for (int fn = 0; fn < 2; ++fn) {
        int c = n0 + fn * 16 + (l & 15);
#pragma unroll
        for (int j = 0; j < 4; ++j) {
          int row = m0 + w * 16 + (l >> 4) * 4 + j;
          doutT[(size_t)row * (TLEN * 256) + c] += acc[fn][j];
        }
      }
    } else if (t < 30) {
      attn8(A, catn, (blk - 128) * 8, smem, tid, w, l);
    }
    if (t < 30) gbar(A.cnt, A.gen);
  }
}

// ---------------- fp32 GEMM 32x32 (hdec projection, one-off) ---------------------
__global__ __launch_bounds__(256) void k_gemm32(const float* __restrict__ A, int lda,
                                                const float* __restrict__ W, int ldw,
                                                const float* __restrict__ bias,
                                                float* __restrict__ out, int ldo, int K) {
  __shared__ float As[16][36];
  __shared__ float Bs[16][36];
  int m0 = blockIdx.x * 32, n0 = blockIdx.y * 32;
  int tid = threadIdx.x;
  int ty = tid >> 4, tx = tid & 15;
  float acc[2][2] = {};
  int lr = tid >> 2, lq = tid & 3;
  for (int k0 = 0; k0 < K; k0 += 16) {
    __syncthreads();
    if (tid < 128) {
      float4 a = *(const float4*)(A + (size_t)(m0 + lr) * lda + k0 + lq * 4);
      As[lq * 4 + 0][lr] = a.x; As[lq * 4 + 1][lr] = a.y;
      As[lq * 4 + 2][lr] = a.z; As[lq * 4 + 3][lr] = a.w;
      float4 b = *(const float4*)(W + (size_t)(n0 + lr) * ldw + k0 + lq * 4);
      Bs[lq * 4 + 0][lr] = b.x; Bs[lq * 4 + 1][lr] = b.y;
      Bs[lq * 4 + 2][lr] = b.z; Bs[lq * 4 + 3][lr] = b.w;
    }
    __syncthreads();
#pragma unroll
    for (int kk = 0; kk < 16; ++kk) {
      float2 av = *(const float2*)&As[kk][ty * 2];
      float2 bv = *(const float2*)&Bs[kk][tx * 2];
      acc[0][0] += av.x * bv.x; acc[0][1] += av.x * bv.y;
      acc[1][0] += av.y * bv.x; acc[1][1] += av.y * bv.y;
    }
  }
  float2 bv = make_float2(0.f, 0.f);
  if (bias) bv = *(const float2*)&bias[n0 + tx * 2];
#pragma unroll
  for (int i = 0; i < 2; ++i) {
    float2 o;
    o.x = acc[i][0] + bv.x; o.y = acc[i][1] + bv.y;
    *(float2*)(out + (size_t)(m0 + ty * 2 + i) * ldo + n0 + tx * 2) = o;
  }
}

// ---------------- hcat = [hf | hb] -----------------------------------------------
__global__ __launch_bounds__(256) void k_hcat(const float* __restrict__ enc_out,
                                              float* __restrict__ hcat) {
  int b = blockIdx.x;
  int k = blockIdx.y * 256 + threadIdx.x;
  float v = (k < 256) ? enc_out[(size_t)b * 16384 + 31 * 512 + k]
                      : enc_out[(size_t)b * 16384 + k];
  hcat[(size_t)b * 512 + k] = v;
}

// ---------------- h0 fp32 -> bf16 into cat0[512:768] -----------------------------
__global__ __launch_bounds__(256) void k_h2b(const float* __restrict__ h,
                                             u16* __restrict__ cat0) {
  int row = blockIdx.x, c = threadIdx.x;
  cat0[(size_t)row * 768 + 512 + c] = f2b(h[(size_t)row * 256 + c]);
}

// ---------------- zero t=0 slice -------------------------------------------------
__global__ __launch_bounds__(256) void k_zero0(float* __restrict__ outp) {
  outp[(size_t)blockIdx.x * (TLEN * 256) + threadIdx.x] = 0.f;
}

extern "C" void kernel_launch(void* const* d_in, const int* in_sizes, int n_in,
                              void* d_out, int out_size, void* d_ws, size_t ws_size,
                              hipStream_t stream) {
  (void)in_sizes; (void)n_in; (void)out_size; (void)ws_size;
  const int* src = (const int*)d_in[0];
  const int* trg = (const int*)d_in[1];
  const float* enc_emb = (const float*)d_in[2];
  const float* eWih_f = (const float*)d_in[3];
  const float* eWhh_f = (const float*)d_in[4];
  const float* ebih_f = (const float*)d_in[5];
  const float* ebhh_f = (const float*)d_in[6];
  const float* eWih_b = (const float*)d_in[7];
  const float* eWhh_b = (const float*)d_in[8];
  const float* ebih_b = (const float*)d_in[9];
  const float* ebhh_b = (const float*)d_in[10];
  const float* Wproj = (const float*)d_in[11];
  const float* bproj = (const float*)d_in[12];
  const float* dec_emb = (const float*)d_in[13];
  const float* Wattn = (const float*)d_in[14];
  const float* battn = (const float*)d_in[15];
  const float* v_attn = (const float*)d_in[16];
  const float* dWih = (const float*)d_in[17];
  const float* dWhh = (const float*)d_in[18];
  const float* dbih = (const float*)d_in[19];
  const float* dbhh = (const float*)d_in[20];
  const float* Wfc = (const float*)d_in[21];
  const float* bfc = (const float*)d_in[22];
  float* dout = (float*)d_out;

  char* base = (char*)d_ws;
  size_t off = 0;
  auto alloc = [&](size_t bytes) {
    void* p = base + off;
    off += (bytes + 255) & ~(size_t)255;
    return p;
  };
  unsigned* bar  = (unsigned*)alloc(256);
  float* enc_out = (float*)alloc((size_t)BSZ * SLEN * 512 * 4);
  u16* enc_b     = (u16*)alloc((size_t)BSZ * SLEN * 512 * 2);
  u16* enc_pre_b = (u16*)alloc((size_t)BSZ * SLEN * 256 * 2);
  float* tabf    = (float*)alloc((size_t)64 * 768 * 4);
  float* tabb    = (float*)alloc((size_t)64 * 768 * 4);
  float* tabd    = (float*)alloc((size_t)256 * 768 * 4);
  float* hcat    = (float*)alloc((size_t)BSZ * 512 * 4);
  float* h0f     = (float*)alloc((size_t)BSZ * 256 * 4);
  float* h1f     = (float*)alloc((size_t)BSZ * 256 * 4);
  u16* Whhf_b    = (u16*)alloc((size_t)768 * 256 * 2);
  u16* Whhb_b    = (u16*)alloc((size_t)768 * 256 * 2);
  u16* We_b      = (u16*)alloc((size_t)256 * 512 * 2);
  u16* Wd_b      = (u16*)alloc((size_t)256 * 256 * 2);
  u16* Wg        = (u16*)alloc((size_t)1024 * 768 * 2);
  u16* Wfc_b     = (u16*)alloc((size_t)256 * 768 * 2);
  u16* cat0      = (u16*)alloc((size_t)BSZ * 768 * 2);
  u16* cat1      = (u16*)alloc((size_t)BSZ * 768 * 2);
  (void)alloc(65536);  // pad: attn8 A-fragments may read 16 rows past block range

  k_init_bar<<<1, 64, 0, stream>>>(bar);

  // tables + weight packs
  k_gi_table<<<dim3(64, 3), 256, 0, stream>>>(enc_emb, eWih_f, EDIM, ebih_f, tabf);
  k_gi_table<<<dim3(64, 3), 256, 0, stream>>>(enc_emb, eWih_b, EDIM, ebih_b, tabb);
  k_gi_table<<<dim3(256, 3), 256, 0, stream>>>(dec_emb, dWih, 640, dbih, tabd);
  k_pack<<<dim3(768), 256, 0, stream>>>(Whhf_b, eWhh_f, 256, 0, 256);
  k_pack<<<dim3(768), 256, 0, stream>>>(Whhb_b, eWhh_b, 256, 0, 256);
  k_pack<<<dim3(256), 256, 0, stream>>>(We_b, Wattn, 768, 256, 512);
  k_pack<<<dim3(256), 256, 0, stream>>>(Wd_b, Wattn, 768, 0, 256);
  k_pack<<<dim3(256), 256, 0, stream>>>(Wfc_b, Wfc, 768, 0, 768);
  k_pack_gates<<<dim3(1024), 256, 0, stream>>>(Wg, dWih, dWhh);

  // encoder: one persistent kernel, 32 internal steps
  {
    EncArgs ea{enc_out, enc_b, src, Whhf_b, Whhb_b, ebhh_f, ebhh_b, tabf, tabb,
               bar, bar + 1};
    k_enc<<<dim3(256), dim3(256), 0, stream>>>(ea);
  }

  // hdec = [hf|hb] @ Wproj.T + bproj; bf16 into cat0[512:768]
  k_hcat<<<dim3(BSZ, 2), 256, 0, stream>>>(enc_out, hcat);
  k_gemm32<<<dim3(BSZ / 32, 8), 256, 0, stream>>>(hcat, 512, Wproj, 512, bproj, h0f, 256, 512);
  k_h2b<<<dim3(BSZ), 256, 0, stream>>>(h0f, cat0);

  // enc_pre (bf16) = enc_out @ We.T + battn
  k_bgemm_b16<<<dim3(256, 4), 256, 0, stream>>>(enc_b, 512, We_b, 512, battn,
                                                enc_pre_b, 256, 512);
  k_zero0<<<dim3(BSZ), 256, 0, stream>>>(dout);

  // decoder: one persistent kernel, 31 internal steps
  {
    DecArgs da{enc_b, enc_pre_b, v_attn, Wd_b, Wg, Wfc_b, tabd, dbhh, bfc, trg,
               cat0, cat1, h0f, h1f, dout, bar, bar + 1};
    k_dec<<<dim3(256), dim3(256), 0, stream>>>(da);
  }
}

// Round 6
// 6365.482 us; speedup vs baseline: 1.0468x; 1.0468x over previous
//
#include <hip/hip_runtime.h>
#include <math.h>

#define BSZ 1024
#define SLEN 32
#define TLEN 32
#define EDIM 128
#define NBLK 256u

typedef unsigned short u16;
typedef __attribute__((ext_vector_type(8))) short bf16x8;
typedef __attribute__((ext_vector_type(4))) float f32x4;

__device__ __forceinline__ float sgm(float x) { return 1.0f / (1.0f + __expf(-x)); }
__device__ __forceinline__ float tanh_fast(float x) {
  float e = __expf(-2.0f * fabsf(x));
  float t = (1.0f - e) / (1.0f + e);
  return copysignf(t, x);
}

__device__ __forceinline__ u16 f2b(float f) {
  union { float f; unsigned u; } v; v.f = f;
  unsigned r = v.u + 0x7fffu + ((v.u >> 16) & 1u);
  return (u16)(r >> 16);
}
__device__ __forceinline__ float b2f(u16 h) {
  union { unsigned u; float f; } v; v.u = ((unsigned)h) << 16; return v.f;
}
__device__ __forceinline__ void unpk(unsigned p, float& x, float& y) {
  union { unsigned u; float f; } a, b;
  a.u = p << 16; b.u = p & 0xffff0000u;
  x = a.f; y = b.f;
}

typedef __attribute__((address_space(1))) const void gv_t;
typedef __attribute__((address_space(3))) void lv_t;
__device__ __forceinline__ void gload16(const void* g, void* l) {
  __builtin_amdgcn_global_load_lds((gv_t*)g, (lv_t*)l, 16, 0, 0);
}

// ------------- broadcast slot grid barrier (no RMW contention) -------------------
// slots: 256 entries, 64B-padded. Arrival: block b release-stores gen k to its own
// slot (parallel across blocks). Wait: thread t polls slot[t] (reads only).
__device__ __forceinline__ void gbar(unsigned* slots, unsigned k) {
  __syncthreads();
  if (threadIdx.x == 0)
    __hip_atomic_store(slots + (size_t)blockIdx.x * 16, k, __ATOMIC_RELEASE,
                       __HIP_MEMORY_SCOPE_AGENT);
  unsigned* my = slots + (size_t)threadIdx.x * 16;
  while (__hip_atomic_load(my, __ATOMIC_ACQUIRE, __HIP_MEMORY_SCOPE_AGENT) < k)
    __builtin_amdgcn_s_sleep(4);
  __syncthreads();
}

__global__ __launch_bounds__(256) void k_init_bar(unsigned* p) {
  p[blockIdx.x * 256 + threadIdx.x] = 0u;
}

// ---------------- gi tables: tab[v][g] = bih[g] + emb[v]@Wih[g,:E] (fp32) ---------
__global__ __launch_bounds__(256) void k_gi_table(const float* __restrict__ emb,
                                                  const float* __restrict__ Wih, int ldw,
                                                  const float* __restrict__ bih,
                                                  float* __restrict__ tab) {
  int v = blockIdx.x;
  int g = blockIdx.y * 256 + threadIdx.x;
  __shared__ float e[EDIM];
  if (threadIdx.x < EDIM) e[threadIdx.x] = emb[v * EDIM + threadIdx.x];
  __syncthreads();
  const float4* w4 = (const float4*)(Wih + (size_t)g * ldw);
  float acc = 0.f;
#pragma unroll
  for (int j = 0; j < EDIM / 4; ++j) {
    float4 w = w4[j];
    acc += w.x * e[4 * j] + w.y * e[4 * j + 1] + w.z * e[4 * j + 2] + w.w * e[4 * j + 3];
  }
  tab[(size_t)v * 768 + g] = acc + bih[g];
}

// ---------------- fp32 -> bf16 weight pack ---------------------------------------
__global__ __launch_bounds__(256) void k_pack(u16* __restrict__ dst,
                                              const float* __restrict__ src, int ld,
                                              int off, int n) {
  int r = blockIdx.x;
  for (int c = threadIdx.x; c < n; c += 256)
    dst[(size_t)r * n + c] = f2b(src[(size_t)r * ld + off + c]);
}

// gates B matrix (1024 x 768)
__global__ __launch_bounds__(256) void k_pack_gates(u16* __restrict__ Wg,
                                                    const float* __restrict__ dWih,
                                                    const float* __restrict__ dWhh) {
  int r = blockIdx.x;
  for (int c = threadIdx.x; c < 768; c += 256) {
    float v;
    if (r < 512)      v = (c < 512) ? dWih[(size_t)r * 640 + 128 + c] : dWhh[(size_t)r * 256 + (c - 512)];
    else if (r < 768) v = (c < 512) ? dWih[(size_t)r * 640 + 128 + c] : 0.f;
    else              v = (c < 512) ? 0.f : dWhh[(size_t)(r - 256) * 256 + (c - 512)];
    Wg[(size_t)r * 768 + c] = f2b(v);
  }
}

// ---------------- bf16 MFMA GEMM 128x64 (enc_pre) --------------------------------
__global__ __launch_bounds__(256) void k_bgemm_b16(const u16* __restrict__ A, int lda,
                                                   const u16* __restrict__ B, int ldb,
                                                   const float* __restrict__ bias,
                                                   u16* __restrict__ out, int ldo, int K) {
  __shared__ u16 sA[128 * 64];
  __shared__ u16 sB[64 * 64];
  int m0 = blockIdx.x * 128, n0 = blockIdx.y * 64;
  int tid = threadIdx.x, w = tid >> 6, l = tid & 63;
  int wr = w >> 1, wc = w & 1;
  f32x4 acc[4][2] = {};
  for (int k0 = 0; k0 < K; k0 += 64) {
    __syncthreads();
#pragma unroll
    for (int i = 0; i < 4; ++i) {
      int chunk = i * 4 + w;
      int d = chunk * 1024 + l * 16;
      int lg = d ^ (((d >> 7) & 7) << 4);
      int row = lg >> 7, kb = lg & 127;
      gload16((const char*)(A + (size_t)(m0 + row) * lda + k0) + kb, (char*)sA + chunk * 1024);
    }
#pragma unroll
    for (int i = 0; i < 2; ++i) {
      int chunk = i * 4 + w;
      int d = chunk * 1024 + l * 16;
      int lg = d ^ (((d >> 7) & 7) << 4);
      int row = lg >> 7, kb = lg & 127;
      gload16((const char*)(B + (size_t)(n0 + row) * ldb + k0) + kb, (char*)sB + chunk * 1024);
    }
    __syncthreads();
#pragma unroll
    for (int kk = 0; kk < 2; ++kk) {
      bf16x8 av[4], bv[2];
#pragma unroll
      for (int fm = 0; fm < 4; ++fm) {
        int row = wr * 64 + fm * 16 + (l & 15);
        int addr = (row * 128 + kk * 64 + (l >> 4) * 16) ^ ((row & 7) << 4);
        av[fm] = *(const bf16x8*)((const char*)sA + addr);
      }
#pragma unroll
      for (int fn = 0; fn < 2; ++fn) {
        int row = wc * 32 + fn * 16 + (l & 15);
        int addr = (row * 128 + kk * 64 + (l >> 4) * 16) ^ ((row & 7) << 4);
        bv[fn] = *(const bf16x8*)((const char*)sB + addr);
      }
#pragma unroll
      for (int fm = 0; fm < 4; ++fm)
#pragma unroll
        for (int fn = 0; fn < 2; ++fn)
          acc[fm][fn] = __builtin_amdgcn_mfma_f32_16x16x32_bf16(av[fm], bv[fn], acc[fm][fn], 0, 0, 0);
    }
  }
#pragma unroll
  for (int fn = 0; fn < 2; ++fn) {
    int c = n0 + wc * 32 + fn * 16 + (l & 15);
    float bb = bias ? bias[c] : 0.f;
#pragma unroll
    for (int fm = 0; fm < 4; ++fm) {
      int r = m0 + wr * 64 + fm * 16 + (l >> 4) * 4;
#pragma unroll
      for (int j = 0; j < 4; ++j)
        out[(size_t)(r + j) * ldo + c] = f2b(acc[fm][fn][j] + bb);
    }
  }
}

// ---------------- shared 64x32 bf16 MFMA tile (4 waves x 16 rows, 32 cols) -------
__device__ __forceinline__ void tile_gemm64x32(const u16* Ab, int lda, const u16* Bb,
                                               int ldb, int K, u16* sA, u16* sB, int w,
                                               int l, f32x4* acc) {
  for (int k0 = 0; k0 < K; k0 += 64) {
    __syncthreads();
#pragma unroll
    for (int i = 0; i < 2; ++i) {
      int chunk = i * 4 + w;
      int d = chunk * 1024 + l * 16;
      int lg = d ^ (((d >> 7) & 7) << 4);
      int row = lg >> 7, kb = lg & 127;
      gload16((const char*)(Ab + (size_t)row * lda + k0) + kb, (char*)sA + chunk * 1024);
    }
    {
      int d = w * 1024 + l * 16;
      int lg = d ^ (((d >> 7) & 7) << 4);
      int row = lg >> 7, kb = lg & 127;
      gload16((const char*)(Bb + (size_t)row * ldb + k0) + kb, (char*)sB + w * 1024);
    }
    __syncthreads();
#pragma unroll
    for (int kk = 0; kk < 2; ++kk) {
      int arow = w * 16 + (l & 15);
      int aaddr = (arow * 128 + kk * 64 + (l >> 4) * 16) ^ ((arow & 7) << 4);
      bf16x8 av = *(const bf16x8*)((const char*)sA + aaddr);
#pragma unroll
      for (int fn = 0; fn < 2; ++fn) {
        int brow = fn * 16 + (l & 15);
        int baddr = (brow * 128 + kk * 64 + (l >> 4) * 16) ^ ((brow & 7) << 4);
        bf16x8 bv = *(const bf16x8*)((const char*)sB + baddr);
        acc[fn] = __builtin_amdgcn_mfma_f32_16x16x32_bf16(av, bv, acc[fn], 0, 0, 0);
      }
    }
  }
}

// ---------------- persistent encoder (slot barrier) ------------------------------
struct EncArgs {
  float* enc_out; u16* enc_b; const int* src;
  const u16* Whhf; const u16* Whhb;
  const float* bhhf; const float* bhhb;
  const float* tabf; const float* tabb;
  unsigned* slots;
};

__global__ __launch_bounds__(256) void k_enc(EncArgs E) {
  __shared__ __align__(16) char smem[20992];
  u16* sA = (u16*)smem;
  u16* sB = (u16*)(smem + 8192);
  int* tokL = (int*)(smem + 20480);
  int tile = blockIdx.x;
  int dir = tile >> 7, rem = tile & 127;
  int m0 = (rem >> 3) * 64, c0 = (rem & 7) * 32;
  int tid = threadIdx.x, w = tid >> 6, l = tid & 63;
  const u16* Whh = dir ? E.Whhb : E.Whhf;
  const float* bhh = dir ? E.bhhb : E.bhhf;
  const float* tab = dir ? E.tabb : E.tabf;
  unsigned bk = 0;
  for (int s = 0; s < SLEN; ++s) {
    int s_store = dir ? (SLEN - 1 - s) : s;
    int s_prev = dir ? (s_store + 1) : (s_store - 1);
    if (tid < 64) tokL[tid] = E.src[(size_t)(m0 + tid) * SLEN + s_store];
    __syncthreads();
    f32x4 acc[3][2] = {};
    if (s > 0) {
      const u16* hp = E.enc_b + (size_t)s_prev * 512 + dir * 256;
      for (int k0 = 0; k0 < 256; k0 += 64) {
        __syncthreads();
#pragma unroll
        for (int i = 0; i < 2; ++i) {
          int chunk = i * 4 + w;
          int d = chunk * 1024 + l * 16;
          int lg = d ^ (((d >> 7) & 7) << 4);
          int row = lg >> 7, kb = lg & 127;
          gload16((const char*)(hp + (size_t)(m0 + row) * 16384 + k0) + kb,
                  (char*)sA + chunk * 1024);
        }
#pragma unroll
        for (int i = 0; i < 3; ++i) {
          int chunk = i * 4 + w;
          int d = chunk * 1024 + l * 16;
          int lg = d ^ (((d >> 7) & 7) << 4);
          int tr = lg >> 7, kb = lg & 127;
          int g = tr >> 5, cc = tr & 31;
          gload16((const char*)(Whh + (size_t)(g * 256 + c0 + cc) * 256 + k0) + kb,
                  (char*)sB + chunk * 1024);
        }
        __syncthreads();
#pragma unroll
        for (int kk = 0; kk < 2; ++kk) {
          int arow = w * 16 + (l & 15);
          int aaddr = (arow * 128 + kk * 64 + (l >> 4) * 16) ^ ((arow & 7) << 4);
          bf16x8 av = *(const bf16x8*)((const char*)sA + aaddr);
#pragma unroll
          for (int g = 0; g < 3; ++g)
#pragma unroll
            for (int fn = 0; fn < 2; ++fn) {
              int br = g * 32 + fn * 16 + (l & 15);
              int baddr = (br * 128 + kk * 64 + (l >> 4) * 16) ^ ((br & 7) << 4);
              bf16x8 bv = *(const bf16x8*)((const char*)sB + baddr);
              acc[g][fn] = __builtin_amdgcn_mfma_f32_16x16x32_bf16(av, bv, acc[g][fn], 0, 0, 0);
            }
        }
      }
    }
#pragma unroll
    for (int fn = 0; fn < 2; ++fn) {
      int c = c0 + fn * 16 + (l & 15);
      float bR = bhh[c], bZ = bhh[256 + c], bN = bhh[512 + c];
#pragma unroll
      for (int j = 0; j < 4; ++j) {
        int rr = w * 16 + (l >> 4) * 4 + j;
        int row = m0 + rr;
        const float* tb = tab + (size_t)tokL[rr] * 768 + c;
        float hold = (s > 0) ? E.enc_out[((size_t)row * SLEN + s_prev) * 512 + dir * 256 + c] : 0.f;
        float rg = sgm(tb[0] + acc[0][fn][j] + bR);
        float zg = sgm(tb[256] + acc[1][fn][j] + bZ);
        float ng = tanh_fast(tb[512] + rg * (acc[2][fn][j] + bN));
        float hn = (1.f - zg) * ng + zg * hold;
        size_t oi = ((size_t)row * SLEN + s_store) * 512 + dir * 256 + c;
        E.enc_out[oi] = hn;
        E.enc_b[oi] = f2b(hn);
      }
    }
    if (s < SLEN - 1) gbar(E.slots, ++bk);
  }
}

// ---------------- persistent decoder (slot barrier) ------------------------------
struct DecArgs {
  const u16* enc_b; const u16* enc_pre_b; const float* v_attn;
  const u16* Wd_b; const u16* Wg; const u16* Wfc_b;
  const float* tabd; const float* dbhh; const float* bfc;
  const int* trg;
  u16* cat0; u16* cat1; float* h0f; float* h1f; float* dout;
  unsigned* slots;
};

// fused attention for 8 rows (b0..b0+7): hWd (MFMA) + scores + softmax + ctx
__device__ void attn8(const DecArgs& A, u16* catn, int b0, char* smem, int tid, int w,
                      int l) {
  float* hwS = (float*)smem;           // 8 x 256
  float* vS = (float*)(smem + 8192);   // 256
  float* awS = (float*)(smem + 9216);  // 8 x 32
  vS[tid] = A.v_attn[tid];
  // hWd: wave w covers attn cols [64w, 64w+64)
  f32x4 acc[4] = {};
  for (int k0 = 0; k0 < 256; k0 += 32) {
    bf16x8 av = *(const bf16x8*)(catn + (size_t)(b0 + (l & 15)) * 768 + 512 + k0 + (l >> 4) * 8);
#pragma unroll
    for (int fn = 0; fn < 4; ++fn) {
      bf16x8 bv = *(const bf16x8*)(A.Wd_b + (size_t)(w * 64 + fn * 16 + (l & 15)) * 256 +
                                   k0 + (l >> 4) * 8);
      acc[fn] = __builtin_amdgcn_mfma_f32_16x16x32_bf16(av, bv, acc[fn], 0, 0, 0);
    }
  }
#pragma unroll
  for (int fn = 0; fn < 4; ++fn) {
    int c = w * 64 + fn * 16 + (l & 15);
#pragma unroll
    for (int j = 0; j < 4; ++j) {
      int r = (l >> 4) * 4 + j;
      if (r < 8) hwS[r * 256 + c] = acc[fn][j];
    }
  }
  __syncthreads();
  // scores: thread -> (r = tid>>5, s = tid&31)
  int r = tid >> 5, s = tid & 31;
  const u16* ep = A.enc_pre_b + ((size_t)(b0 + r) * SLEN + s) * 256;
  float sum = 0.f;
  for (int a0 = 0; a0 < 256; a0 += 8) {
    bf16x8 pk = *(const bf16x8*)(ep + a0);
    float4 h0 = *(const float4*)&hwS[r * 256 + a0];
    float4 h1 = *(const float4*)&hwS[r * 256 + a0 + 4];
    float4 v0 = *(const float4*)&vS[a0];
    float4 v1 = *(const float4*)&vS[a0 + 4];
    sum += v0.x * tanh_fast(b2f((u16)pk[0]) + h0.x) + v0.y * tanh_fast(b2f((u16)pk[1]) + h0.y) +
           v0.z * tanh_fast(b2f((u16)pk[2]) + h0.z) + v0.w * tanh_fast(b2f((u16)pk[3]) + h0.w) +
           v1.x * tanh_fast(b2f((u16)pk[4]) + h1.x) + v1.y * tanh_fast(b2f((u16)pk[5]) + h1.y) +
           v1.z * tanh_fast(b2f((u16)pk[6]) + h1.z) + v1.w * tanh_fast(b2f((u16)pk[7]) + h1.w);
  }
  float m = sum;
#pragma unroll
  for (int o = 16; o >= 1; o >>= 1) m = fmaxf(m, __shfl_xor(m, o));
  float e = __expf(sum - m), ss = e;
#pragma unroll
  for (int o = 16; o >= 1; o >>= 1) ss += __shfl_xor(ss, o);
  awS[r * 32 + s] = e / ss;
  __syncthreads();
  // ctx: thread -> cols [2*tid, 2*tid+2)
  int c = tid * 2;
#pragma unroll
  for (int rr = 0; rr < 8; ++rr) {
    float ax = 0.f, ay = 0.f;
    const u16* eb = A.enc_b + (size_t)(b0 + rr) * (SLEN * 512) + c;
#pragma unroll 8
    for (int si = 0; si < 32; ++si) {
      float a = awS[rr * 32 + si];
      unsigned pk = *(const unsigned*)(eb + si * 512);
      float x, y; unpk(pk, x, y);
      ax += a * x; ay += a * y;
    }
    *(unsigned*)(catn + (size_t)(b0 + rr) * 768 + c) =
        (unsigned)f2b(ax) | ((unsigned)f2b(ay) << 16);
  }
}

__global__ __launch_bounds__(256) void k_dec(DecArgs A) {
  __shared__ __align__(16) char smem[24832];
  int blk = blockIdx.x, tid = threadIdx.x, w = tid >> 6, l = tid & 63;
  unsigned bk = 0;
  // prologue: attn(0) on blocks >=128 (reads cat0[512:768]=h0, writes cat0[0:512])
  if (blk >= 128) attn8(A, A.cat0, (blk - 128) * 8, smem, tid, w, l);
  gbar(A.slots, ++bk);
  for (int t = 0; t <= 30; ++t) {
    u16* catc = (t & 1) ? A.cat1 : A.cat0;
    u16* catn = (t & 1) ? A.cat0 : A.cat1;
    const float* hc = (t & 1) ? A.h1f : A.h0f;
    float* hn = (t & 1) ? A.h0f : A.h1f;
    float* doutT = A.dout + (size_t)(t + 1) * 256;
    // ---- Phase A: gates (blk<128) || logits-ctx (blk>=128) ----
    if (blk < 128) {
      u16* sA = (u16*)smem;
      u16* sB = (u16*)(smem + 8192);
      int* tokL = (int*)(smem + 24576);
      int m0 = (blk >> 3) * 64, c0 = (blk & 7) * 32;
      if (tid < 64) tokL[tid] = A.trg[(size_t)(m0 + tid) * TLEN + t];
      f32x4 acc[4][2] = {};
      for (int k0 = 0; k0 < 768; k0 += 64) {
        __syncthreads();
#pragma unroll
        for (int i = 0; i < 2; ++i) {
          int chunk = i * 4 + w;
          int d = chunk * 1024 + l * 16;
          int lg = d ^ (((d >> 7) & 7) << 4);
          int row = lg >> 7, kb = lg & 127;
          gload16((const char*)(catc + (size_t)(m0 + row) * 768 + k0) + kb,
                  (char*)sA + chunk * 1024);
        }
#pragma unroll
        for (int i = 0; i < 4; ++i) {
          int chunk = i * 4 + w;
          int d = chunk * 1024 + l * 16;
          int lg = d ^ (((d >> 7) & 7) << 4);
          int tr = lg >> 7, kb = lg & 127;
          int g = tr >> 5, cc = tr & 31;
          gload16((const char*)(A.Wg + (size_t)(g * 256 + c0 + cc) * 768 + k0) + kb,
                  (char*)sB + chunk * 1024);
        }
        __syncthreads();
#pragma unroll
        for (int kk = 0; kk < 2; ++kk) {
          int arow = w * 16 + (l & 15);
          int aaddr = (arow * 128 + kk * 64 + (l >> 4) * 16) ^ ((arow & 7) << 4);
          bf16x8 av = *(const bf16x8*)((const char*)sA + aaddr);
#pragma unroll
          for (int g = 0; g < 4; ++g)
#pragma unroll
            for (int fn = 0; fn < 2; ++fn) {
              int br = g * 32 + fn * 16 + (l & 15);
              int baddr = (br * 128 + kk * 64 + (l >> 4) * 16) ^ ((br & 7) << 4);
              bf16x8 bv = *(const bf16x8*)((const char*)sB + baddr);
              acc[g][fn] = __builtin_amdgcn_mfma_f32_16x16x32_bf16(av, bv, acc[g][fn], 0, 0, 0);
            }
        }
      }
#pragma unroll
      for (int fn = 0; fn < 2; ++fn) {
        int c = c0 + fn * 16 + (l & 15);
        float bR = A.dbhh[c], bZ = A.dbhh[256 + c], bN = A.dbhh[512 + c];
#pragma unroll
        for (int j = 0; j < 4; ++j) {
          int rr = w * 16 + (l >> 4) * 4 + j;
          int row = m0 + rr;
          const float* tb = A.tabd + (size_t)tokL[rr] * 768 + c;
          float rg = sgm(tb[0] + acc[0][fn][j] + bR);
          float zg = sgm(tb[256] + acc[1][fn][j] + bZ);
          float ng = tanh_fast(tb[512] + acc[2][fn][j] + rg * (acc[3][fn][j] + bN));
          float hold = hc[(size_t)row * 256 + c];
          float hv = (1.f - zg) * ng + zg * hold;
          hn[(size_t)row * 256 + c] = hv;
          catn[(size_t)row * 768 + 512 + c] = f2b(hv);
        }
      }
    } else {
      int idx = blk - 128;
      int m0 = (idx >> 3) * 64, n0 = (idx & 7) * 32;
      u16* sA = (u16*)smem;
      u16* sB = (u16*)(smem + 8192);
      f32x4 acc[2] = {};
      tile_gemm64x32(catc + (size_t)m0 * 768, 768, A.Wfc_b + (size_t)n0 * 768 + 256, 768,
                     512, sA, sB, w, l, acc);
#pragma unroll
      for (int fn = 0; fn < 2; ++fn) {
        int c = n0 + fn * 16 + (l & 15);
        float bb = A.bfc[c];
#pragma unroll
        for (int j = 0; j < 4; ++j) {
          int row = m0 + w * 16 + (l >> 4) * 4 + j;
          doutT[(size_t)row * (TLEN * 256) + c] = acc[fn][j] + bb;
        }
      }
    }
    gbar(A.slots, ++bk);
    // ---- Phase B: logits-hn += (blk<128) || attn(t+1) (blk>=128) ----
    if (blk < 128) {
      int m0 = (blk >> 3) * 64, n0 = (blk & 7) * 32;
      u16* sA = (u16*)smem;
      u16* sB = (u16*)(smem + 8192);
      f32x4 acc[2] = {};
      tile_gemm64x32(catn + (size_t)m0 * 768 + 512, 768, A.Wfc_b + (size_t)n0 * 768, 768,
                     256, sA, sB, w, l, acc);
#pragma unroll
      for (int fn = 0; fn < 2; ++fn) {
        int c = n0 + fn * 16 + (l & 15);
#pragma unroll
        for (int j = 0; j < 4; ++j) {
          int row = m0 + w * 16 + (l >> 4) * 4 + j;
          doutT[(size_t)row * (TLEN * 256) + c] += acc[fn][j];
        }
      }
    } else if (t < 30) {
      attn8(A, catn, (blk - 128) * 8, smem, tid, w, l);
    }
    if (t < 30) gbar(A.slots, ++bk);
  }
}

// ---------------- fp32 GEMM 32x32 (hdec projection, one-off) ---------------------
__global__ __launch_bounds__(256) void k_gemm32(const float* __restrict__ A, int lda,
                                                const float* __restrict__ W, int ldw,
                                                const float* __restrict__ bias,
                                                float* __restrict__ out, int ldo, int K) {
  __shared__ float As[16][36];
  __shared__ float Bs[16][36];
  int m0 = blockIdx.x * 32, n0 = blockIdx.y * 32;
  int tid = threadIdx.x;
  int ty = tid >> 4, tx = tid & 15;
  float acc[2][2] = {};
  int lr = tid >> 2, lq = tid & 3;
  for (int k0 = 0; k0 < K; k0 += 16) {
    __syncthreads();
    if (tid < 128) {
      float4 a = *(const float4*)(A + (size_t)(m0 + lr) * lda + k0 + lq * 4);
      As[lq * 4 + 0][lr] = a.x; As[lq * 4 + 1][lr] = a.y;
      As[lq * 4 + 2][lr] = a.z; As[lq * 4 + 3][lr] = a.w;
      float4 b = *(const float4*)(W + (size_t)(n0 + lr) * ldw + k0 + lq * 4);
      Bs[lq * 4 + 0][lr] = b.x; Bs[lq * 4 + 1][lr] = b.y;
      Bs[lq * 4 + 2][lr] = b.z; Bs[lq * 4 + 3][lr] = b.w;
    }
    __syncthreads();
#pragma unroll
    for (int kk = 0; kk < 16; ++kk) {
      float2 av = *(const float2*)&As[kk][ty * 2];
      float2 bv = *(const float2*)&Bs[kk][tx * 2];
      acc[0][0] += av.x * bv.x; acc[0][1] += av.x * bv.y;
      acc[1][0] += av.y * bv.x; acc[1][1] += av.y * bv.y;
    }
  }
  float2 bv = make_float2(0.f, 0.f);
  if (bias) bv = *(const float2*)&bias[n0 + tx * 2];
#pragma unroll
  for (int i = 0; i < 2; ++i) {
    float2 o;
    o.x = acc[i][0] + bv.x; o.y = acc[i][1] + bv.y;
    *(float2*)(out + (size_t)(m0 + ty * 2 + i) * ldo + n0 + tx * 2) = o;
  }
}

// ---------------- hcat = [hf | hb] -----------------------------------------------
__global__ __launch_bounds__(256) void k_hcat(const float* __restrict__ enc_out,
                                              float* __restrict__ hcat) {
  int b = blockIdx.x;
  int k = blockIdx.y * 256 + threadIdx.x;
  float v = (k < 256) ? enc_out[(size_t)b * 16384 + 31 * 512 + k]
                      : enc_out[(size_t)b * 16384 + k];
  hcat[(size_t)b * 512 + k] = v;
}

// ---------------- h0 fp32 -> bf16 into cat0[512:768] -----------------------------
__global__ __launch_bounds__(256) void k_h2b(const float* __restrict__ h,
                                             u16* __restrict__ cat0) {
  int row = blockIdx.x, c = threadIdx.x;
  cat0[(size_t)row * 768 + 512 + c] = f2b(h[(size_t)row * 256 + c]);
}

// ---------------- zero t=0 slice -------------------------------------------------
__global__ __launch_bounds__(256) void k_zero0(float* __restrict__ outp) {
  outp[(size_t)blockIdx.x * (TLEN * 256) + threadIdx.x] = 0.f;
}

extern "C" void kernel_launch(void* const* d_in, const int* in_sizes, int n_in,
                              void* d_out, int out_size, void* d_ws, size_t ws_size,
                              hipStream_t stream) {
  (void)in_sizes; (void)n_in; (void)out_size; (void)ws_size;
  const int* src = (const int*)d_in[0];
  const int* trg = (const int*)d_in[1];
  const float* enc_emb = (const float*)d_in[2];
  const float* eWih_f = (const float*)d_in[3];
  const float* eWhh_f = (const float*)d_in[4];
  const float* ebih_f = (const float*)d_in[5];
  const float* ebhh_f = (const float*)d_in[6];
  const float* eWih_b = (const float*)d_in[7];
  const float* eWhh_b = (const float*)d_in[8];
  const float* ebih_b = (const float*)d_in[9];
  const float* ebhh_b = (const float*)d_in[10];
  const float* Wproj = (const float*)d_in[11];
  const float* bproj = (const float*)d_in[12];
  const float* dec_emb = (const float*)d_in[13];
  const float* Wattn = (const float*)d_in[14];
  const float* battn = (const float*)d_in[15];
  const float* v_attn = (const float*)d_in[16];
  const float* dWih = (const float*)d_in[17];
  const float* dWhh = (const float*)d_in[18];
  const float* dbih = (const float*)d_in[19];
  const float* dbhh = (const float*)d_in[20];
  const float* Wfc = (const float*)d_in[21];
  const float* bfc = (const float*)d_in[22];
  float* dout = (float*)d_out;

  char* base = (char*)d_ws;
  size_t off = 0;
  auto alloc = [&](size_t bytes) {
    void* p = base + off;
    off += (bytes + 255) & ~(size_t)255;
    return p;
  };
  unsigned* slots = (unsigned*)alloc(256 * 16 * 4);  // 64B-padded per-block slot
  float* enc_out = (float*)alloc((size_t)BSZ * SLEN * 512 * 4);
  u16* enc_b     = (u16*)alloc((size_t)BSZ * SLEN * 512 * 2);
  u16* enc_pre_b = (u16*)alloc((size_t)BSZ * SLEN * 256 * 2);
  float* tabf    = (float*)alloc((size_t)64 * 768 * 4);
  float* tabb    = (float*)alloc((size_t)64 * 768 * 4);
  float* tabd    = (float*)alloc((size_t)256 * 768 * 4);
  float* hcat    = (float*)alloc((size_t)BSZ * 512 * 4);
  float* h0f     = (float*)alloc((size_t)BSZ * 256 * 4);
  float* h1f     = (float*)alloc((size_t)BSZ * 256 * 4);
  u16* Whhf_b    = (u16*)alloc((size_t)768 * 256 * 2);
  u16* Whhb_b    = (u16*)alloc((size_t)768 * 256 * 2);
  u16* We_b      = (u16*)alloc((size_t)256 * 512 * 2);
  u16* Wd_b      = (u16*)alloc((size_t)256 * 256 * 2);
  u16* Wg        = (u16*)alloc((size_t)1024 * 768 * 2);
  u16* Wfc_b     = (u16*)alloc((size_t)256 * 768 * 2);
  u16* cat0      = (u16*)alloc((size_t)BSZ * 768 * 2);
  u16* cat1      = (u16*)alloc((size_t)BSZ * 768 * 2);
  (void)alloc(65536);  // pad: attn8 A-fragments may read 16 rows past block range

  k_init_bar<<<dim3(16), 256, 0, stream>>>(slots);

  // tables + weight packs
  k_gi_table<<<dim3(64, 3), 256, 0, stream>>>(enc_emb, eWih_f, EDIM, ebih_f, tabf);
  k_gi_table<<<dim3(64, 3), 256, 0, stream>>>(enc_emb, eWih_b, EDIM, ebih_b, tabb);
  k_gi_table<<<dim3(256, 3), 256, 0, stream>>>(dec_emb, dWih, 640, dbih, tabd);
  k_pack<<<dim3(768), 256, 0, stream>>>(Whhf_b, eWhh_f, 256, 0, 256);
  k_pack<<<dim3(768), 256, 0, stream>>>(Whhb_b, eWhh_b, 256, 0, 256);
  k_pack<<<dim3(256), 256, 0, stream>>>(We_b, Wattn, 768, 256, 512);
  k_pack<<<dim3(256), 256, 0, stream>>>(Wd_b, Wattn, 768, 0, 256);
  k_pack<<<dim3(256), 256, 0, stream>>>(Wfc_b, Wfc, 768, 0, 768);
  k_pack_gates<<<dim3(1024), 256, 0, stream>>>(Wg, dWih, dWhh);

  // encoder: one persistent kernel, 32 internal steps
  {
    EncArgs ea{enc_out, enc_b, src, Whhf_b, Whhb_b, ebhh_f, ebhh_b, tabf, tabb, slots};
    k_enc<<<dim3(256), dim3(256), 0, stream>>>(ea);
  }

  // hdec = [hf|hb] @ Wproj.T + bproj; bf16 into cat0[512:768]
  k_hcat<<<dim3(BSZ, 2), 256, 0, stream>>>(enc_out, hcat);
  k_gemm32<<<dim3(BSZ / 32, 8), 256, 0, stream>>>(hcat, 512, Wproj, 512, bproj, h0f, 256, 512);
  k_h2b<<<dim3(BSZ), 256, 0, stream>>>(h0f, cat0);

  // enc_pre (bf16) = enc_out @ We.T + battn
  k_bgemm_b16<<<dim3(256, 4), 256, 0, stream>>>(enc_b, 512, We_b, 512, battn,
                                                enc_pre_b, 256, 512);
  k_zero0<<<dim3(BSZ), 256, 0, stream>>>(dout);

  // re-zero slots for the decoder (stream-ordered after k_enc)
  k_init_bar<<<dim3(16), 256, 0, stream>>>(slots);

  // decoder: one persistent kernel, 31 internal steps
  {
    DecArgs da{enc_b, enc_pre_b, v_attn, Wd_b, Wg, Wfc_b, tabd, dbhh, bfc, trg,
               cat0, cat1, h0f, h1f, dout, slots};
    k_dec<<<dim3(256), dim3(256), 0, stream>>>(da);
  }
}

// Round 7
// 4303.863 us; speedup vs baseline: 1.5483x; 1.4790x over previous
//
#include <hip/hip_runtime.h>
#include <math.h>

#define BSZ 1024
#define SLEN 32
#define TLEN 32
#define EDIM 128
#define NT 512
#define HLD 264    // u16 row stride for bf16 h in LDS (+16B pad -> 2-way bank alias, free)
#define HFLD 260   // f32 row stride
#define CTXLD 520  // u16 row stride for ctx
#define HWLD 260   // f32 row stride for hWd

typedef unsigned short u16;
typedef __attribute__((ext_vector_type(8))) short bf16x8;
typedef __attribute__((ext_vector_type(4))) float f32x4;

__device__ __forceinline__ float sgm(float x) { return 1.0f / (1.0f + __expf(-x)); }
__device__ __forceinline__ float tanh_fast(float x) {
  float e = __expf(-2.0f * fabsf(x));
  float t = (1.0f - e) / (1.0f + e);
  return copysignf(t, x);
}
__device__ __forceinline__ u16 f2b(float f) {
  union { float f; unsigned u; } v; v.f = f;
  unsigned r = v.u + 0x7fffu + ((v.u >> 16) & 1u);
  return (u16)(r >> 16);
}
__device__ __forceinline__ float b2f(u16 h) {
  union { unsigned u; float f; } v; v.u = ((unsigned)h) << 16; return v.f;
}

typedef __attribute__((address_space(1))) const void gv_t;
typedef __attribute__((address_space(3))) void lv_t;
__device__ __forceinline__ void gload16(const void* g, void* l) {
  __builtin_amdgcn_global_load_lds((gv_t*)g, (lv_t*)l, 16, 0, 0);
}

// ---------------- gi tables: tab[v][g] = bih[g] + emb[v]@Wih[g,:E] ----------------
__global__ __launch_bounds__(256) void k_gi_table(const float* __restrict__ emb,
                                                  const float* __restrict__ Wih, int ldw,
                                                  const float* __restrict__ bih,
                                                  float* __restrict__ tab) {
  int v = blockIdx.x;
  int g = blockIdx.y * 256 + threadIdx.x;
  __shared__ float e[EDIM];
  if (threadIdx.x < EDIM) e[threadIdx.x] = emb[v * EDIM + threadIdx.x];
  __syncthreads();
  const float4* w4 = (const float4*)(Wih + (size_t)g * ldw);
  float acc = 0.f;
#pragma unroll
  for (int j = 0; j < EDIM / 4; ++j) {
    float4 w = w4[j];
    acc += w.x * e[4 * j] + w.y * e[4 * j + 1] + w.z * e[4 * j + 2] + w.w * e[4 * j + 3];
  }
  tab[(size_t)v * 768 + g] = acc + bih[g];
}

// ---------------- fp32 -> bf16 weight pack ---------------------------------------
__global__ __launch_bounds__(256) void k_pack(u16* __restrict__ dst,
                                              const float* __restrict__ src, int ld,
                                              int off, int n) {
  int r = blockIdx.x;
  for (int c = threadIdx.x; c < n; c += 256)
    dst[(size_t)r * n + c] = f2b(src[(size_t)r * ld + off + c]);
}

// gates B matrix (1024 x 768): R,Z: [dWih_ctx|dWhh]; Ni: [dWih_ctx_n|0]; Nh: [0|dWhh_n]
__global__ __launch_bounds__(256) void k_pack_gates(u16* __restrict__ Wg,
                                                    const float* __restrict__ dWih,
                                                    const float* __restrict__ dWhh) {
  int r = blockIdx.x;
  for (int c = threadIdx.x; c < 768; c += 256) {
    float v;
    if (r < 512)      v = (c < 512) ? dWih[(size_t)r * 640 + 128 + c] : dWhh[(size_t)r * 256 + (c - 512)];
    else if (r < 768) v = (c < 512) ? dWih[(size_t)r * 640 + 128 + c] : 0.f;
    else              v = (c < 512) ? 0.f : dWhh[(size_t)(r - 256) * 256 + (c - 512)];
    Wg[(size_t)r * 768 + c] = f2b(v);
  }
}

// ---------------- bf16 MFMA GEMM 128x64: out = A.B^T + bias ----------------------
template <bool B16OUT>
__global__ __launch_bounds__(256) void k_bgemm(const u16* __restrict__ A, int lda,
                                               const u16* __restrict__ B, int ldb,
                                               const float* __restrict__ bias,
                                               void* __restrict__ outv, int ldo, int K) {
  __shared__ u16 sA[128 * 64];
  __shared__ u16 sB[64 * 64];
  int m0 = blockIdx.x * 128, n0 = blockIdx.y * 64;
  int tid = threadIdx.x, w = tid >> 6, l = tid & 63;
  int wr = w >> 1, wc = w & 1;
  f32x4 acc[4][2] = {};
  for (int k0 = 0; k0 < K; k0 += 64) {
    __syncthreads();
#pragma unroll
    for (int i = 0; i < 4; ++i) {
      int chunk = i * 4 + w;
      int d = chunk * 1024 + l * 16;
      int lg = d ^ (((d >> 7) & 7) << 4);
      int row = lg >> 7, kb = lg & 127;
      gload16((const char*)(A + (size_t)(m0 + row) * lda + k0) + kb, (char*)sA + chunk * 1024);
    }
#pragma unroll
    for (int i = 0; i < 2; ++i) {
      int chunk = i * 4 + w;
      int d = chunk * 1024 + l * 16;
      int lg = d ^ (((d >> 7) & 7) << 4);
      int row = lg >> 7, kb = lg & 127;
      gload16((const char*)(B + (size_t)(n0 + row) * ldb + k0) + kb, (char*)sB + chunk * 1024);
    }
    __syncthreads();
#pragma unroll
    for (int kk = 0; kk < 2; ++kk) {
      bf16x8 av[4], bv[2];
#pragma unroll
      for (int fm = 0; fm < 4; ++fm) {
        int row = wr * 64 + fm * 16 + (l & 15);
        int addr = (row * 128 + kk * 64 + (l >> 4) * 16) ^ ((row & 7) << 4);
        av[fm] = *(const bf16x8*)((const char*)sA + addr);
      }
#pragma unroll
      for (int fn = 0; fn < 2; ++fn) {
        int row = wc * 32 + fn * 16 + (l & 15);
        int addr = (row * 128 + kk * 64 + (l >> 4) * 16) ^ ((row & 7) << 4);
        bv[fn] = *(const bf16x8*)((const char*)sB + addr);
      }
#pragma unroll
      for (int fm = 0; fm < 4; ++fm)
#pragma unroll
        for (int fn = 0; fn < 2; ++fn)
          acc[fm][fn] = __builtin_amdgcn_mfma_f32_16x16x32_bf16(av[fm], bv[fn], acc[fm][fn], 0, 0, 0);
    }
  }
#pragma unroll
  for (int fn = 0; fn < 2; ++fn) {
    int c = n0 + wc * 32 + fn * 16 + (l & 15);
    float bb = bias ? bias[c] : 0.f;
#pragma unroll
    for (int fm = 0; fm < 4; ++fm) {
      int r = m0 + wr * 64 + fm * 16 + (l >> 4) * 4;
#pragma unroll
      for (int j = 0; j < 4; ++j) {
        float val = acc[fm][fn][j] + bb;
        if (B16OUT) ((u16*)outv)[(size_t)(r + j) * ldo + c] = f2b(val);
        else        ((float*)outv)[(size_t)(r + j) * ldo + c] = val;
      }
    }
  }
}

// ---------------- batched logits GEMM: bcat(31744x768) @ Wfc^T -> dout scatter ----
__global__ __launch_bounds__(256) void k_bgemm_logits(const u16* __restrict__ A,
                                                      const u16* __restrict__ B,
                                                      const float* __restrict__ bias,
                                                      float* __restrict__ dout) {
  __shared__ u16 sA[128 * 64];
  __shared__ u16 sB[64 * 64];
  int m0 = blockIdx.x * 128, n0 = blockIdx.y * 64;
  int tid = threadIdx.x, w = tid >> 6, l = tid & 63;
  int wr = w >> 1, wc = w & 1;
  f32x4 acc[4][2] = {};
  for (int k0 = 0; k0 < 768; k0 += 64) {
    __syncthreads();
#pragma unroll
    for (int i = 0; i < 4; ++i) {
      int chunk = i * 4 + w;
      int d = chunk * 1024 + l * 16;
      int lg = d ^ (((d >> 7) & 7) << 4);
      int row = lg >> 7, kb = lg & 127;
      gload16((const char*)(A + (size_t)(m0 + row) * 768 + k0) + kb, (char*)sA + chunk * 1024);
    }
#pragma unroll
    for (int i = 0; i < 2; ++i) {
      int chunk = i * 4 + w;
      int d = chunk * 1024 + l * 16;
      int lg = d ^ (((d >> 7) & 7) << 4);
      int row = lg >> 7, kb = lg & 127;
      gload16((const char*)(B + (size_t)(n0 + row) * 768 + k0) + kb, (char*)sB + chunk * 1024);
    }
    __syncthreads();
#pragma unroll
    for (int kk = 0; kk < 2; ++kk) {
      bf16x8 av[4], bv[2];
#pragma unroll
      for (int fm = 0; fm < 4; ++fm) {
        int row = wr * 64 + fm * 16 + (l & 15);
        int addr = (row * 128 + kk * 64 + (l >> 4) * 16) ^ ((row & 7) << 4);
        av[fm] = *(const bf16x8*)((const char*)sA + addr);
      }
#pragma unroll
      for (int fn = 0; fn < 2; ++fn) {
        int row = wc * 32 + fn * 16 + (l & 15);
        int addr = (row * 128 + kk * 64 + (l >> 4) * 16) ^ ((row & 7) << 4);
        bv[fn] = *(const bf16x8*)((const char*)sB + addr);
      }
#pragma unroll
      for (int fm = 0; fm < 4; ++fm)
#pragma unroll
        for (int fn = 0; fn < 2; ++fn)
          acc[fm][fn] = __builtin_amdgcn_mfma_f32_16x16x32_bf16(av[fm], bv[fn], acc[fm][fn], 0, 0, 0);
    }
  }
#pragma unroll
  for (int fn = 0; fn < 2; ++fn) {
    int c = n0 + wc * 32 + fn * 16 + (l & 15);
    float bb = bias[c];
#pragma unroll
    for (int fm = 0; fm < 4; ++fm) {
#pragma unroll
      for (int j = 0; j < 4; ++j) {
        int gr = m0 + wr * 64 + fm * 16 + (l >> 4) * 4 + j;
        int tt = gr >> 10, b = gr & 1023;
        dout[(size_t)b * (TLEN * 256) + (size_t)(tt + 1) * 256 + c] = acc[fm][fn][j] + bb;
      }
    }
  }
}

// ---------------- persistent encoder: block owns 16 rows, loops s, NO sync -------
struct EncArgs {
  u16* enc_b; u16* hcatB; const int* src;
  const u16* Whhf; const u16* Whhb;
  const float* bhhf; const float* bhhb;
  const float* tabf; const float* tabb;
};

__global__ __launch_bounds__(NT) void k_enc_p(EncArgs E) {
  __shared__ float hF[2][16 * HFLD];
  __shared__ u16 hB[2][16 * HLD];
  __shared__ int toks[16 * 32];
  int r0 = blockIdx.x * 16;
  int tid = threadIdx.x, w = tid >> 6, l = tid & 63;
  for (int i = tid; i < 16 * 256; i += NT) {
    int r = i >> 8, c = i & 255;
    hF[0][r * HFLD + c] = 0.f; hF[1][r * HFLD + c] = 0.f;
    hB[0][r * HLD + c] = 0;    hB[1][r * HLD + c] = 0;
  }
  for (int i = tid; i < 512; i += NT)
    toks[i] = E.src[(size_t)(r0 + (i >> 5)) * SLEN + (i & 31)];
  __syncthreads();
  for (int s = 0; s < SLEN; ++s) {
    f32x4 ae[2][3][2] = {};
    if (s > 0) {
#pragma unroll
      for (int dir = 0; dir < 2; ++dir) {
        const u16* Whh = dir ? E.Whhb : E.Whhf;
        for (int k0 = 0; k0 < 256; k0 += 32) {
          bf16x8 av = *(const bf16x8*)(hB[dir] + (l & 15) * HLD + k0 + (l >> 4) * 8);
#pragma unroll
          for (int g = 0; g < 3; ++g)
#pragma unroll
            for (int fn = 0; fn < 2; ++fn) {
              bf16x8 bv = *(const bf16x8*)(Whh + (size_t)(g * 256 + w * 32 + fn * 16 + (l & 15)) * 256 + k0 + (l >> 4) * 8);
              ae[dir][g][fn] = __builtin_amdgcn_mfma_f32_16x16x32_bf16(av, bv, ae[dir][g][fn], 0, 0, 0);
            }
        }
      }
    }
    __syncthreads();
#pragma unroll
    for (int dir = 0; dir < 2; ++dir) {
      int s_store = dir ? (SLEN - 1 - s) : s;
      const float* tab = dir ? E.tabb : E.tabf;
      const float* bhh = dir ? E.bhhb : E.bhhf;
#pragma unroll
      for (int fn = 0; fn < 2; ++fn) {
        int c = w * 32 + fn * 16 + (l & 15);
        float bR = bhh[c], bZ = bhh[256 + c], bN = bhh[512 + c];
#pragma unroll
        for (int j = 0; j < 4; ++j) {
          int row = (l >> 4) * 4 + j;
          const float* tb = tab + (size_t)toks[row * 32 + s_store] * 768 + c;
          float rg = sgm(tb[0] + ae[dir][0][fn][j] + bR);
          float zg = sgm(tb[256] + ae[dir][1][fn][j] + bZ);
          float ng = tanh_fast(tb[512] + rg * (ae[dir][2][fn][j] + bN));
          float hold = hF[dir][row * HFLD + c];
          float hv = (1.f - zg) * ng + zg * hold;
          hF[dir][row * HFLD + c] = hv;
          u16 hb16 = f2b(hv);
          hB[dir][row * HLD + c] = hb16;
          E.enc_b[((size_t)(r0 + row) * SLEN + s_store) * 512 + dir * 256 + c] = hb16;
        }
      }
    }
    __syncthreads();
  }
  // hcat = [hf | hb] (bf16)
  for (int i = tid; i < 16 * 512; i += NT) {
    int r = i >> 9, c = i & 511;
    E.hcatB[(size_t)(r0 + r) * 512 + c] =
        (c < 256) ? hB[0][r * HLD + c] : hB[1][r * HLD + (c - 256)];
  }
}

// ---------------- persistent decoder: block owns 16 rows, loops t, NO sync -------
struct DecArgs {
  const u16* enc_b; const u16* enc_pre_b; const float* v_attn;
  const u16* Wd_b; const u16* Wg;
  const float* tabd; const float* dbhh;
  const int* trg; const float* h0f;
  u16* bcat;
};

__global__ __launch_bounds__(NT) void k_dec_p(DecArgs A) {
  __shared__ float hF[16 * HFLD];
  __shared__ u16 hB[16 * HLD];
  __shared__ u16 ctxB[16 * CTXLD];
  __shared__ float hwS[16 * HWLD];
  __shared__ float awS[16 * 33];
  __shared__ float vS[256];
  __shared__ int toks[16 * 32];
  int r0 = blockIdx.x * 16;
  int tid = threadIdx.x, w = tid >> 6, l = tid & 63;
  // seed h = hdec
  for (int i = tid; i < 16 * 256; i += NT) {
    int r = i >> 8, c = i & 255;
    float v = A.h0f[(size_t)(r0 + r) * 256 + c];
    hF[r * HFLD + c] = v;
    hB[r * HLD + c] = f2b(v);
  }
  for (int i = tid; i < 256; i += NT) vS[i] = A.v_attn[i];
  for (int i = tid; i < 512; i += NT)
    toks[i] = A.trg[(size_t)(r0 + (i >> 5)) * TLEN + (i & 31)];
  __syncthreads();
  for (int t = 0; t < TLEN - 1; ++t) {
    // ---- 1) hWd = h @ Wd^T : wave w -> cols [w*32, w*32+32) ----
    {
      f32x4 a2[2] = {};
      for (int k0 = 0; k0 < 256; k0 += 32) {
        bf16x8 av = *(const bf16x8*)(hB + (l & 15) * HLD + k0 + (l >> 4) * 8);
#pragma unroll
        for (int fn = 0; fn < 2; ++fn) {
          bf16x8 bv = *(const bf16x8*)(A.Wd_b + (size_t)(w * 32 + fn * 16 + (l & 15)) * 256 + k0 + (l >> 4) * 8);
          a2[fn] = __builtin_amdgcn_mfma_f32_16x16x32_bf16(av, bv, a2[fn], 0, 0, 0);
        }
      }
#pragma unroll
      for (int fn = 0; fn < 2; ++fn) {
        int c = w * 32 + fn * 16 + (l & 15);
#pragma unroll
        for (int j = 0; j < 4; ++j)
          hwS[((l >> 4) * 4 + j) * HWLD + c] = a2[fn][j];
      }
    }
    __syncthreads();
    // ---- 2) scores + softmax: thread -> (r = tid>>5, s = tid&31) ----
    {
      int r = tid >> 5, s = tid & 31;
      const u16* ep = A.enc_pre_b + ((size_t)(r0 + r) * SLEN + s) * 256;
      float sum = 0.f;
      for (int a0 = 0; a0 < 256; a0 += 8) {
        bf16x8 pk = *(const bf16x8*)(ep + a0);
#pragma unroll
        for (int q = 0; q < 8; ++q)
          sum += vS[a0 + q] * tanh_fast(b2f((u16)pk[q]) + hwS[r * HWLD + a0 + q]);
      }
      float m = sum;
#pragma unroll
      for (int o = 16; o >= 1; o >>= 1) m = fmaxf(m, __shfl_xor(m, o));
      float e = __expf(sum - m), ss = e;
#pragma unroll
      for (int o = 16; o >= 1; o >>= 1) ss += __shfl_xor(ss, o);
      awS[r * 33 + s] = e / ss;
    }
    __syncthreads();
    // ---- 3) ctx = aw @ enc_b slice; write ctxB + bcat[.,256:768] ----
#pragma unroll
    for (int i = 0; i < 2; ++i) {
      int task = tid + i * NT;
      int r = task >> 6, c = (task & 63) * 8;
      float a8[8] = {};
      const u16* eb = A.enc_b + ((size_t)(r0 + r) * SLEN) * 512 + c;
#pragma unroll 4
      for (int s2 = 0; s2 < 32; ++s2) {
        float a = awS[r * 33 + s2];
        bf16x8 pk = *(const bf16x8*)(eb + s2 * 512);
#pragma unroll
        for (int q = 0; q < 8; ++q) a8[q] += a * b2f((u16)pk[q]);
      }
      bf16x8 o;
#pragma unroll
      for (int q = 0; q < 8; ++q) o[q] = (short)f2b(a8[q]);
      *(bf16x8*)(ctxB + r * CTXLD + c) = o;
      *(bf16x8*)(A.bcat + ((size_t)t * BSZ + r0 + r) * 768 + 256 + c) = o;
    }
    __syncthreads();
    // ---- 4) gates = [ctx|h] @ Wg^T : wave w -> gate cols [w*32, w*32+32) ----
    f32x4 ag[4][2] = {};
    for (int k0 = 0; k0 < 768; k0 += 32) {
      bf16x8 av = (k0 < 512)
          ? *(const bf16x8*)(ctxB + (l & 15) * CTXLD + k0 + (l >> 4) * 8)
          : *(const bf16x8*)(hB + (l & 15) * HLD + (k0 - 512) + (l >> 4) * 8);
#pragma unroll
      for (int g = 0; g < 4; ++g)
#pragma unroll
        for (int fn = 0; fn < 2; ++fn) {
          bf16x8 bv = *(const bf16x8*)(A.Wg + (size_t)(g * 256 + w * 32 + fn * 16 + (l & 15)) * 768 + k0 + (l >> 4) * 8);
          ag[g][fn] = __builtin_amdgcn_mfma_f32_16x16x32_bf16(av, bv, ag[g][fn], 0, 0, 0);
        }
    }
    __syncthreads();
    // ---- 5) GRU epilogue: write h (LDS) + bcat[.,0:256] ----
#pragma unroll
    for (int fn = 0; fn < 2; ++fn) {
      int c = w * 32 + fn * 16 + (l & 15);
      float bR = A.dbhh[c], bZ = A.dbhh[256 + c], bN = A.dbhh[512 + c];
#pragma unroll
      for (int j = 0; j < 4; ++j) {
        int row = (l >> 4) * 4 + j;
        const float* tb = A.tabd + (size_t)toks[row * 32 + t] * 768 + c;
        float rg = sgm(tb[0] + ag[0][fn][j] + bR);
        float zg = sgm(tb[256] + ag[1][fn][j] + bZ);
        float ng = tanh_fast(tb[512] + ag[2][fn][j] + rg * (ag[3][fn][j] + bN));
        float hold = hF[row * HFLD + c];
        float hv = (1.f - zg) * ng + zg * hold;
        hF[row * HFLD + c] = hv;
        u16 hb16 = f2b(hv);
        hB[row * HLD + c] = hb16;
        A.bcat[((size_t)t * BSZ + r0 + row) * 768 + c] = hb16;
      }
    }
    __syncthreads();
  }
}

// ---------------- zero t=0 slice -------------------------------------------------
__global__ __launch_bounds__(256) void k_zero0(float* __restrict__ outp) {
  outp[(size_t)blockIdx.x * (TLEN * 256) + threadIdx.x] = 0.f;
}

extern "C" void kernel_launch(void* const* d_in, const int* in_sizes, int n_in,
                              void* d_out, int out_size, void* d_ws, size_t ws_size,
                              hipStream_t stream) {
  (void)in_sizes; (void)n_in; (void)out_size; (void)ws_size;
  const int* src = (const int*)d_in[0];
  const int* trg = (const int*)d_in[1];
  const float* enc_emb = (const float*)d_in[2];
  const float* eWih_f = (const float*)d_in[3];
  const float* eWhh_f = (const float*)d_in[4];
  const float* ebih_f = (const float*)d_in[5];
  const float* ebhh_f = (const float*)d_in[6];
  const float* eWih_b = (const float*)d_in[7];
  const float* eWhh_b = (const float*)d_in[8];
  const float* ebih_b = (const float*)d_in[9];
  const float* ebhh_b = (const float*)d_in[10];
  const float* Wproj = (const float*)d_in[11];
  const float* bproj = (const float*)d_in[12];
  const float* dec_emb = (const float*)d_in[13];
  const float* Wattn = (const float*)d_in[14];
  const float* battn = (const float*)d_in[15];
  const float* v_attn = (const float*)d_in[16];
  const float* dWih = (const float*)d_in[17];
  const float* dWhh = (const float*)d_in[18];
  const float* dbih = (const float*)d_in[19];
  const float* dbhh = (const float*)d_in[20];
  const float* Wfc = (const float*)d_in[21];
  const float* bfc = (const float*)d_in[22];
  float* dout = (float*)d_out;

  char* base = (char*)d_ws;
  size_t off = 0;
  auto alloc = [&](size_t bytes) {
    void* p = base + off;
    off += (bytes + 255) & ~(size_t)255;
    return p;
  };
  u16* enc_b     = (u16*)alloc((size_t)BSZ * SLEN * 512 * 2);
  u16* enc_pre_b = (u16*)alloc((size_t)BSZ * SLEN * 256 * 2);
  u16* bcat      = (u16*)alloc((size_t)31 * BSZ * 768 * 2);
  float* tabf    = (float*)alloc((size_t)64 * 768 * 4);
  float* tabb    = (float*)alloc((size_t)64 * 768 * 4);
  float* tabd    = (float*)alloc((size_t)256 * 768 * 4);
  u16* hcatB     = (u16*)alloc((size_t)BSZ * 512 * 2);
  float* h0f     = (float*)alloc((size_t)BSZ * 256 * 4);
  u16* Whhf_b    = (u16*)alloc((size_t)768 * 256 * 2);
  u16* Whhb_b    = (u16*)alloc((size_t)768 * 256 * 2);
  u16* We_b      = (u16*)alloc((size_t)256 * 512 * 2);
  u16* Wd_b      = (u16*)alloc((size_t)256 * 256 * 2);
  u16* Wproj_b   = (u16*)alloc((size_t)256 * 512 * 2);
  u16* Wg        = (u16*)alloc((size_t)1024 * 768 * 2);
  u16* Wfc_b     = (u16*)alloc((size_t)256 * 768 * 2);

  // tables + weight packs
  k_gi_table<<<dim3(64, 3), 256, 0, stream>>>(enc_emb, eWih_f, EDIM, ebih_f, tabf);
  k_gi_table<<<dim3(64, 3), 256, 0, stream>>>(enc_emb, eWih_b, EDIM, ebih_b, tabb);
  k_gi_table<<<dim3(256, 3), 256, 0, stream>>>(dec_emb, dWih, 640, dbih, tabd);
  k_pack<<<dim3(768), 256, 0, stream>>>(Whhf_b, eWhh_f, 256, 0, 256);
  k_pack<<<dim3(768), 256, 0, stream>>>(Whhb_b, eWhh_b, 256, 0, 256);
  k_pack<<<dim3(256), 256, 0, stream>>>(We_b, Wattn, 768, 256, 512);
  k_pack<<<dim3(256), 256, 0, stream>>>(Wd_b, Wattn, 768, 0, 256);
  k_pack<<<dim3(256), 256, 0, stream>>>(Wproj_b, Wproj, 512, 0, 512);
  k_pack<<<dim3(256), 256, 0, stream>>>(Wfc_b, Wfc, 768, 0, 768);
  k_pack_gates<<<dim3(1024), 256, 0, stream>>>(Wg, dWih, dWhh);

  // encoder: persistent, 64 blocks x 16 rows, zero grid sync
  {
    EncArgs ea{enc_b, hcatB, src, Whhf_b, Whhb_b, ebhh_f, ebhh_b, tabf, tabb};
    k_enc_p<<<dim3(64), dim3(NT), 0, stream>>>(ea);
  }

  // hdec = hcat @ Wproj^T + bproj (fp32 out)
  k_bgemm<false><<<dim3(8, 4), 256, 0, stream>>>(hcatB, 512, Wproj_b, 512, bproj, h0f, 256, 512);
  // enc_pre (bf16) = enc_b @ We^T + battn
  k_bgemm<true><<<dim3(256, 4), 256, 0, stream>>>(enc_b, 512, We_b, 512, battn,
                                                  enc_pre_b, 256, 512);
  k_zero0<<<dim3(BSZ), 256, 0, stream>>>(dout);

  // decoder: persistent, 64 blocks x 16 rows, zero grid sync
  {
    DecArgs da{enc_b, enc_pre_b, v_attn, Wd_b, Wg, tabd, dbhh, trg, h0f, bcat};
    k_dec_p<<<dim3(64), dim3(NT), 0, stream>>>(da);
  }

  // deferred logits: [hn|ctx] @ Wfc^T + bfc for all 31 steps at once
  k_bgemm_logits<<<dim3(248, 4), 256, 0, stream>>>(bcat, Wfc_b, bfc, dout);
}